// Round 1
// 41668.240 us; speedup vs baseline: 1.0236x; 1.0236x over previous
//
#include <hip/hip_runtime.h>
#include <math.h>

// Problem constants
#define B 64
#define T 512
#define F 256
#define U 1024
#define NBLK 256
#define NTH 512
#define WPAD 68   // zbuf row stride (floats): 68%32=4 -> conflict-free b128 partial stores

typedef unsigned short ushort_t;
typedef __attribute__((ext_vector_type(8))) _Float16 f16x8_t;  // MFMA A/B frag (4 VGPR)
typedef __attribute__((ext_vector_type(4))) float f32x4_t;     // MFMA C/D frag

// ---------------- workspace layout (BYTE offsets) ----------------
static const size_t OFF_HT2  = 0;                  // fp32 h2 [U][B]: 262144
static const size_t OFF_STATS= 262144;             // fp32 [2 parity][2][B]: 1024
static const size_t OFF_COND = 263424;             // int[512]: 2048
static const size_t OFF_BAR  = 265472;             // int[1024]: 4096
static const size_t OFF_HB   = 269568;             // f16 h [2][3][B][U]: 786432
static const size_t OFF_XB   = 1056000;            // f16 xbuf [B][F]: 32768
static const size_t OFF_PW0  = 1088768;            // f16 [256 g][40 kt][512]: 10485760
static const size_t OFF_PW1  = 11574528;           // f16 [256][64][512]: 16777216
static const size_t OFF_PW2  = 28351744;           // f16 [256][64][512]: 16777216
static const size_t ZERO_BYTES = OFF_PW0;          // state region zeroed each launch
// bar int-offsets (one 64B line each): sub[i]=i*16 (i<8); master=128;
// relay[i]=144+i*16 (i<8); minibar=272.

__device__ __forceinline__ float sigm(float x) {
    return 1.0f / (1.0f + __expf(-x));
}

__device__ __forceinline__ ushort_t f2h(float x) {   // RNE fp32->fp16
    _Float16 h = (_Float16)x;
    union { _Float16 h; ushort_t u; } v; v.h = h;
    return v.u;
}

// ---- write-through (device-coherent) stores: data lands at the coherence
// point, so consumers need NO release fence and NO per-phase acquire inv.
__device__ __forceinline__ void store_uc_u16(ushort_t* p, ushort_t v) {
    asm volatile("global_store_short %0, %1, off sc0 sc1"
                 :: "v"(p), "v"((unsigned)v) : "memory");
}
__device__ __forceinline__ void store_uc_f32(float* p, float v) {
    asm volatile("global_store_dword %0, %1, off sc0 sc1"
                 :: "v"(p), "v"(v) : "memory");
}
__device__ __forceinline__ void store_uc_b64(void* p, unsigned long long v) {
    asm volatile("global_store_dwordx2 %0, %1, off sc0 sc1"
                 :: "v"(p), "v"(v) : "memory");
}
__device__ __forceinline__ void drain_vmem() {
    asm volatile("s_waitcnt vmcnt(0)" ::: "memory");
}

// Fence-free phase sync (round-8). Monotonic epoch; hierarchical arrival
// (8 lines x 32); releaser resets counters, drains, then publishes epoch to
// 8 relay lines (32 pollers/line, not 256/line). Relaxed polls; NO acquire
// fence at exit — freshness is provided by the once-per-step inv at loop top
// (producers store write-through). Insurance acquire-load every 64 spins.
__device__ __forceinline__ void phase_sync(int* bar, int epoch, int g) {
    drain_vmem();        // each wave drains its own (incl. asm) stores
    __syncthreads();
    if (threadIdx.x == 0) {
        int prev = __hip_atomic_fetch_add(bar + (g & 7) * 16, 1,
                                          __ATOMIC_RELAXED, __HIP_MEMORY_SCOPE_AGENT);
        if (prev == 31) {
            int pm = __hip_atomic_fetch_add(bar + 128, 1,
                                            __ATOMIC_RELAXED, __HIP_MEMORY_SCOPE_AGENT);
            if (pm == 7) {
                #pragma unroll
                for (int i = 0; i < 8; ++i)
                    __hip_atomic_store(bar + i * 16, 0, __ATOMIC_RELAXED,
                                       __HIP_MEMORY_SCOPE_AGENT);
                __hip_atomic_store(bar + 128, 0, __ATOMIC_RELAXED,
                                   __HIP_MEMORY_SCOPE_AGENT);
                drain_vmem();   // resets land before epoch publication
                #pragma unroll
                for (int i = 0; i < 8; ++i)
                    __hip_atomic_store(bar + 144 + i * 16, epoch, __ATOMIC_RELAXED,
                                       __HIP_MEMORY_SCOPE_AGENT);
            }
        }
        int* myrelay = bar + 144 + (g & 7) * 16;
        int spins = 0;
        while (__hip_atomic_load(myrelay, __ATOMIC_RELAXED,
                                 __HIP_MEMORY_SCOPE_AGENT) < epoch) {
            __builtin_amdgcn_s_sleep(4);
            if ((++spins & 63) == 0)
                (void)__hip_atomic_load(myrelay, __ATOMIC_ACQUIRE,
                                        __HIP_MEMORY_SCOPE_AGENT);
        }
    }
    __syncthreads();
}

// Prep: decode conditioned_lst (bool-u8 vs int32 sniff), init f16 xbuf.
__global__ void prep_kernel(const unsigned char* __restrict__ condraw,
                            const float* __restrict__ input,
                            unsigned char* __restrict__ wsb) {
    __shared__ int s_not_int32;
    const int tid = threadIdx.x;
    if (tid == 0) s_not_int32 = 0;
    __syncthreads();
    if (tid < 512 && (tid & 3) != 0) {
        if (condraw[tid] != 0) s_not_int32 = 1;
    }
    __syncthreads();
    const int is32 = (s_not_int32 == 0);
    int* condw = (int*)(wsb + OFF_COND);
    if (tid < 512) {
        int cv = is32 ? ((const int*)condraw)[tid] : (int)condraw[tid];
        condw[tid] = (cv != 0) ? 1 : 0;
    }
    ushort_t* xb = (ushort_t*)(wsb + OFF_XB);
    for (int i = tid; i < B * F; i += blockDim.x) {
        const int b = i >> 8, f = i & 255;
        xb[i] = f2h(input[(size_t)b * (T * F) + f]);
    }
}

// Repack fp32 weights -> fp16 in MFMA B-fragment order:
// PW_l[((g*KT + kt)*64 + L)*8 + j] = W_l[k][col], k = kt*32 + (L>>4)*8 + j,
// n = L&15, col = (n>>2)*1024 + g*4 + (n&3)
__global__ void repack_kernel(const float* __restrict__ W0,
                              const float* __restrict__ W1,
                              const float* __restrict__ W2,
                              unsigned char* __restrict__ wsb) {
    ushort_t* P0 = (ushort_t*)(wsb + OFF_PW0);
    ushort_t* P1 = (ushort_t*)(wsb + OFF_PW1);
    ushort_t* P2 = (ushort_t*)(wsb + OFF_PW2);
    const size_t stride = (size_t)gridDim.x * blockDim.x;
    const size_t tid = (size_t)blockIdx.x * blockDim.x + threadIdx.x;
    const size_t N0 = (size_t)256 * 40 * 512;
    const size_t N12 = (size_t)256 * 64 * 512;
    for (size_t i = tid; i < N0; i += stride) {
        const int g = (int)(i / 20480);
        const int r = (int)(i % 20480);
        const int kt = r >> 9, s = r & 511, L = s >> 3, j = s & 7;
        const int k = kt * 32 + ((L >> 4) << 3) + j;
        const int n = L & 15;
        const int col = ((n >> 2) << 10) + (g << 2) + (n & 3);
        P0[i] = f2h(W0[(size_t)k * 4096 + col]);
    }
    for (size_t i = tid; i < N12; i += stride) {
        const int g = (int)(i / 32768);
        const int r = (int)(i % 32768);
        const int kt = r >> 9, s = r & 511, L = s >> 3, j = s & 7;
        const int k = kt * 32 + ((L >> 4) << 3) + j;
        const int n = L & 15;
        const int col = ((n >> 2) << 10) + (g << 2) + (n & 3);
        const size_t src = (size_t)k * 4096 + col;
        P1[i] = f2h(W1[src]);
        P2[i] = f2h(W2[src]);
    }
}

// Round-9: split each layer GEMM into {h-recurrence half, fresh-x half}.
// The h half of step t+1 (L0: kt 8..39, L1/L2: kt 32..63) only needs state
// published earlier in step t, so it is streamed + MFMA-accumulated during
// the dense/LN phase (where 192/256 blocks were idle) into persistent
// per-wave accumulators acc0/acc1/acc2 that survive the grid barrier and
// the once-per-step cache inv (registers). Post-barrier critical path per
// layer phase shrinks to the fresh-x half (L0: 1 kt/wave, L1/L2: 4 kt/wave).
// Wave kt ownership re-split evenly (x: 4wv+c / wv, h: 32+4wv+c / 8+4wv+c);
// the 8-wave zbuf reduce is unchanged (sum of partials is order-free).
__global__ void __launch_bounds__(NTH, 2)
lstm_persistent(const float* __restrict__ input,
                const float* __restrict__ b0, const float* __restrict__ b1,
                const float* __restrict__ b2,
                const float* __restrict__ Wd, const float* __restrict__ bd,
                const float* __restrict__ gamma, const float* __restrict__ beta,
                float* __restrict__ out, unsigned char* __restrict__ wsb) {
    const int g = blockIdx.x;
    const int tid = threadIdx.x;
    const int lane = tid & 63;
    const int wv = __builtin_amdgcn_readfirstlane(tid >> 6);  // 0..7
    const int ln15 = lane & 15;
    const int quad = lane >> 4;
    const int kofs = quad << 3;

    float* hT2 = (float*)(wsb + OFF_HT2);          // fp32 [U][B]
    float* stats = (float*)(wsb + OFF_STATS);
    int* bar = (int*)(wsb + OFF_BAR);
    ushort_t* hb = (ushort_t*)(wsb + OFF_HB);      // f16 [2][3][B][U]
    ushort_t* xb = (ushort_t*)(wsb + OFF_XB);      // f16 [B][F]

    // inv-proof residency (round-7, kept): weights in regs + LDS; cond in LDS.
    __shared__ f16x8_t lds_pw0[40 * 64];     // 40 KB: L0 B-frags
    __shared__ f32x4_t lds_wd4[1024];        // 16 KB: Wd cols (g<64)
    __shared__ float zbuf[128 * WPAD];       // 34.8 KB
    __shared__ int lds_cond[512];            // 2 KB

    const int u0 = g << 2;
    const int f0 = g << 2;

    // B-frags in regs, indexed to the NEW wave kt-split:
    // Bw[0..3]  = x-part kts  (4wv + 0..3)
    // Bw[4..7]  = h-part kts  (32 + 4wv + 0..3)
    f16x8_t Bw1[8], Bw2[8];
    {
        const ushort_t* p1 = (const ushort_t*)(wsb + OFF_PW1) +
                             (size_t)g * 64 * 512 + (size_t)lane * 8;
        const ushort_t* p2 = (const ushort_t*)(wsb + OFF_PW2) +
                             (size_t)g * 64 * 512 + (size_t)lane * 8;
        #pragma unroll
        for (int i = 0; i < 4; ++i) {
            Bw1[i]     = *(const f16x8_t*)(p1 + (size_t)((wv << 2) + i) * 512);
            Bw1[4 + i] = *(const f16x8_t*)(p1 + (size_t)(32 + (wv << 2) + i) * 512);
            Bw2[i]     = *(const f16x8_t*)(p2 + (size_t)((wv << 2) + i) * 512);
            Bw2[4 + i] = *(const f16x8_t*)(p2 + (size_t)(32 + (wv << 2) + i) * 512);
        }
    }
    {
        const f16x8_t* src = (const f16x8_t*)((const ushort_t*)(wsb + OFF_PW0) +
                                              (size_t)g * 40 * 512);
        for (int i = tid; i < 40 * 64; i += NTH) lds_pw0[i] = src[i];
    }
    if (g < 64) {
        for (int k = tid; k < 1024; k += NTH)
            lds_wd4[k] = *(const f32x4_t*)(Wd + (size_t)k * F + f0);
    }
    for (int i = tid; i < 512; i += NTH) lds_cond[i] = ((const int*)(wsb + OFF_COND))[i];

    const int eb = tid & 63;
    const int eu = (tid >> 6) & 3;

    // loop-invariant hoists (survive the per-step inv in registers)
    float bias0[4], bias1[4], bias2[4];
    if (tid < 256) {
        #pragma unroll
        for (int q = 0; q < 4; ++q) {
            bias0[q] = b0[(q << 10) + u0 + eu];
            bias1[q] = b1[(q << 10) + u0 + eu];
            bias2[q] = b2[(q << 10) + u0 + eu];
        }
    }
    float4 gm4 = {0,0,0,0}, bt4 = {0,0,0,0}, bd4 = {0,0,0,0};
    if (g < 64 && wv == 0) {
        gm4 = *(const float4*)(gamma + f0);
        bt4 = *(const float4*)(beta + f0);
        bd4 = *(const float4*)(bd + f0);
    }
    __syncthreads();

    float creg0 = 0.f, creg1 = 0.f, creg2 = 0.f;

    // Persistent accumulators. Invariant on entry to each layer's x-phase:
    // accN holds that layer's h-recurrence partial for the CURRENT step
    // (zero at t=0 since h_{-1}=0).
    f32x4_t acc0[4], acc1[4], acc2[4];
    #pragma unroll
    for (int mt = 0; mt < 4; ++mt) {
        acc0[mt] = (f32x4_t){0.f, 0.f, 0.f, 0.f};
        acc1[mt] = (f32x4_t){0.f, 0.f, 0.f, 0.f};
        acc2[mt] = (f32x4_t){0.f, 0.f, 0.f, 0.f};
    }

    // 4-kt MFMA slab: A cols = (4wv+c)*32 .. +31 of asrc ([B][U] f16),
    // B-frags Bw[boff + c]. Used for x-parts (boff=0) and h-parts (boff=4;
    // h col offset (kg-U) == (4wv+c)*32, same formula).
    auto mm4 = [&](f32x4_t (&acc)[4], const ushort_t* asrc,
                   const f16x8_t (&Bw)[8], const int boff) {
        f16x8_t Ab[4][4];
        const ushort_t* lp0 = asrc + (size_t)ln15 * U + kofs;
        #pragma unroll
        for (int c = 0; c < 4; ++c) {
            const int kg = ((wv << 2) + c) << 5;
            #pragma unroll
            for (int mt = 0; mt < 4; ++mt)
                Ab[c][mt] = *(const f16x8_t*)(lp0 + kg + (size_t)(mt << 4) * U);
        }
        #pragma unroll
        for (int c = 0; c < 4; ++c) {
            #pragma unroll
            for (int mt = 0; mt < 4; ++mt)
                acc[mt] = __builtin_amdgcn_mfma_f32_16x16x32_f16(
                    Ab[c][mt], Bw[boff + c], acc[mt], 0, 0, 0);
        }
    };

    // L0 h-part: kts 8 + 4wv + c (c=0..3); A col offset (kg-F) == (4wv+c)*32.
    auto mm_h0 = [&](f32x4_t (&acc)[4], const ushort_t* hsrc) {
        f16x8_t Ab[4][4];
        const ushort_t* lp0 = hsrc + (size_t)ln15 * U + kofs;
        #pragma unroll
        for (int c = 0; c < 4; ++c) {
            const int kg = ((wv << 2) + c) << 5;
            #pragma unroll
            for (int mt = 0; mt < 4; ++mt)
                Ab[c][mt] = *(const f16x8_t*)(lp0 + kg + (size_t)(mt << 4) * U);
        }
        #pragma unroll
        for (int c = 0; c < 4; ++c) {
            const f16x8_t Bb = lds_pw0[(8 + (wv << 2) + c) * 64 + lane];
            #pragma unroll
            for (int mt = 0; mt < 4; ++mt)
                acc[mt] = __builtin_amdgcn_mfma_f32_16x16x32_f16(
                    Ab[c][mt], Bb, acc[mt], 0, 0, 0);
        }
    };

    // dump acc -> zbuf, zero acc (ready for next step's h-prefetch),
    // 8-wave reduce + gates + h store.
    auto epilogue = [&](f32x4_t (&acc)[4], const float (&bi)[4], float& cr,
                        ushort_t* hdst, float* h32dst) {
        float* zrow = zbuf + (size_t)(wv * 16 + ln15) * WPAD;
        #pragma unroll
        for (int mt = 0; mt < 4; ++mt)
            *(f32x4_t*)(zrow + mt * 16 + (quad << 2)) = acc[mt];
        #pragma unroll
        for (int mt = 0; mt < 4; ++mt) acc[mt] = (f32x4_t){0.f, 0.f, 0.f, 0.f};
        __syncthreads();
        if (tid < 256) {   // gate epilogue: (b=eb, unit u0+eu)
            float z[4];
            #pragma unroll
            for (int q = 0; q < 4; ++q) {
                float s = bi[q];
                #pragma unroll
                for (int w = 0; w < 8; ++w)
                    s += zbuf[(size_t)(w * 16 + q * 4 + eu) * WPAD + eb];
                z[q] = s;
            }
            const float ig = sigm(z[0]);
            const float gg = tanhf(z[1]);
            const float fg = sigm(z[2] + 1.0f);   // forget_bias = 1.0
            const float og = sigm(z[3]);
            const float cn = cr * fg + ig * gg;
            const float hn = og * tanhf(cn);
            cr = cn;
            store_uc_u16(hdst + (size_t)eb * U + u0 + eu, f2h(hn));
            if (h32dst) store_uc_f32(h32dst + (size_t)(u0 + eu) * B + eb, hn);
        }
    };

    int epoch = 0;
    for (int t = 0; t < T; ++t) {
        const int pn = (t & 1) ^ 1;
        ushort_t* h0n = hb + (size_t)(pn * 3 + 0) * B * U;
        ushort_t* h1n = hb + (size_t)(pn * 3 + 1) * B * U;
        ushort_t* h2n = hb + (size_t)(pn * 3 + 2) * B * U;

        // THE one inv per step: wipes L1/L2 so this step's cached state reads
        // are fresh. Weights (regs/LDS) and prefetched accs unaffected.
        __builtin_amdgcn_fence(__ATOMIC_ACQUIRE, "agent");

        // ---- phase 0: L0 fresh-x half (kt = wv, from xb) ----
        {
            f16x8_t Ax[4];
            const ushort_t* lp0 = xb + (wv << 5) + (size_t)ln15 * F + kofs;
            #pragma unroll
            for (int mt = 0; mt < 4; ++mt)
                Ax[mt] = *(const f16x8_t*)(lp0 + (size_t)(mt << 4) * F);
            const f16x8_t Bb = lds_pw0[wv * 64 + lane];
            #pragma unroll
            for (int mt = 0; mt < 4; ++mt)
                acc0[mt] = __builtin_amdgcn_mfma_f32_16x16x32_f16(
                    Ax[mt], Bb, acc0[mt], 0, 0, 0);
        }
        epilogue(acc0, bias0, creg0, h0n, nullptr);
        phase_sync(bar, ++epoch, g);

        // ---- phase 1: L1 fresh-x half (A = h0_t) ----
        mm4(acc1, h0n, Bw1, 0);
        epilogue(acc1, bias1, creg1, h1n, nullptr);
        phase_sync(bar, ++epoch, g);

        // ---- phase 2: L2 fresh-x half (A = h1_t) ----
        mm4(acc2, h1n, Bw2, 0);
        epilogue(acc2, bias2, creg2, h2n, hT2);
        phase_sync(bar, ++epoch, g);

        // ------- phase 3: dense + LN (g<64) overlapped with h-prefetch -------
        if (g < 64) {
            float accd[4] = {0.f, 0.f, 0.f, 0.f};
            const int k0 = wv << 7;   // U/8 = 128 per wave
            #pragma unroll 16
            for (int k = k0; k < k0 + 128; ++k) {
                const float xv = hT2[(size_t)k * B + lane];
                const f32x4_t w4 = lds_wd4[k];
                accd[0] = fmaf(w4.x, xv, accd[0]);
                accd[1] = fmaf(w4.y, xv, accd[1]);
                accd[2] = fmaf(w4.z, xv, accd[2]);
                accd[3] = fmaf(w4.w, xv, accd[3]);
            }
            __syncthreads();
            #pragma unroll
            for (int jj = 0; jj < 4; ++jj)
                zbuf[(size_t)(wv * 16 + jj) * WPAD + lane] = accd[jj];
            __syncthreads();
            if (wv == 0) {
                float yv[4];
                float s = 0.f, ss = 0.f;
                #pragma unroll
                for (int jj = 0; jj < 4; ++jj) {
                    float y = 0.f;
                    #pragma unroll
                    for (int w = 0; w < 8; ++w)
                        y += zbuf[(size_t)(w * 16 + jj) * WPAD + lane];
                    y += (jj == 0) ? bd4.x : (jj == 1) ? bd4.y : (jj == 2) ? bd4.z : bd4.w;
                    yv[jj] = y;
                    s += y;
                    ss += y * y;
                }
                float* st = stats + (size_t)(t & 1) * 2 * B;
                atomicAdd(&st[lane], s);
                atomicAdd(&st[B + lane], ss);
                // mini-sync among 64 dense blocks (monotonic, fence-free)
                if (lane == 0) {
                    drain_vmem();   // wave-wide: stats adds complete
                    __hip_atomic_fetch_add(bar + 272, 1, __ATOMIC_RELAXED,
                                           __HIP_MEMORY_SCOPE_AGENT);
                    const int target = (t + 1) * 64;
                    int spins = 0;
                    while (__hip_atomic_load(bar + 272, __ATOMIC_RELAXED,
                                             __HIP_MEMORY_SCOPE_AGENT) < target) {
                        __builtin_amdgcn_s_sleep(4);
                        if ((++spins & 63) == 0)
                            (void)__hip_atomic_load(bar + 272, __ATOMIC_ACQUIRE,
                                                    __HIP_MEMORY_SCOPE_AGENT);
                    }
                }
                // plain loads: stats lines not cached on this XCD since the
                // step-start inv (atomics bypass), so this fetch is fresh
                const float mu = st[lane] * (1.0f / F);
                const float var = st[B + lane] * (1.0f / F) - mu * mu;
                const float rs = rsqrtf(var + 1e-12f);
                float em[4];
                em[0] = fmaxf((yv[0] - mu) * rs * gm4.x + bt4.x, 0.0f);
                em[1] = fmaxf((yv[1] - mu) * rs * gm4.y + bt4.y, 0.0f);
                em[2] = fmaxf((yv[2] - mu) * rs * gm4.z + bt4.z, 0.0f);
                em[3] = fmaxf((yv[3] - mu) * rs * gm4.w + bt4.w, 0.0f);
                *(float4*)(out + (size_t)lane * (T * F) + (size_t)t * F + f0) =
                    make_float4(em[0], em[1], em[2], em[3]);
                if (t + 1 < T) {
                    float xn[4];
                    if (lds_cond[t + 1] != 0) {
                        const float4 iv = *(const float4*)(input + (size_t)lane * (T * F) +
                                                           (size_t)(t + 1) * F + f0);
                        xn[0] = iv.x; xn[1] = iv.y; xn[2] = iv.z; xn[3] = iv.w;
                    } else {
                        xn[0] = em[0]; xn[1] = em[1]; xn[2] = em[2]; xn[3] = em[3];
                    }
                    unsigned long long pk =
                        (unsigned long long)f2h(xn[0]) |
                        ((unsigned long long)f2h(xn[1]) << 16) |
                        ((unsigned long long)f2h(xn[2]) << 32) |
                        ((unsigned long long)f2h(xn[3]) << 48);
                    store_uc_b64(xb + (size_t)lane * F + f0, pk);
                }
            }
        } else if (g == 64 && wv == 0) {
            // zero other-parity stats for step t+1 (write-through)
            float* st2 = stats + (size_t)((t + 1) & 1) * 2 * B;
            store_uc_f32(&st2[lane], 0.0f);
            store_uc_f32(&st2[B + lane], 0.0f);
        }

        // h-recurrence prefetch for step t+1 (parity(t+1) == pn):
        // A-lines were read by this same wave in phases 1/2 (L1-hit, fresh;
        // no writes intervene) or come fresh from L3 (h2_t). MFMA results
        // live in registers across the barrier and the next step's inv.
        mm_h0(acc0, h0n);            // L0: kt 8+4wv+c   <- h0_t
        mm4(acc1, h1n, Bw1, 4);      // L1: kt 32+4wv+c  <- h1_t
        mm4(acc2, h2n, Bw2, 4);      // L2: kt 32+4wv+c  <- h2_t
        phase_sync(bar, ++epoch, g);
    }
}

extern "C" void kernel_launch(void* const* d_in, const int* in_sizes, int n_in,
                              void* d_out, int out_size, void* d_ws, size_t ws_size,
                              hipStream_t stream) {
    const float* input = (const float*)d_in[0];
    const unsigned char* condraw = (const unsigned char*)d_in[1];
    const float* W0 = (const float*)d_in[2];
    const float* b0 = (const float*)d_in[3];
    const float* W1 = (const float*)d_in[4];
    const float* b1 = (const float*)d_in[5];
    const float* W2 = (const float*)d_in[6];
    const float* b2 = (const float*)d_in[7];
    const float* Wd = (const float*)d_in[8];
    const float* bd = (const float*)d_in[9];
    const float* gamma = (const float*)d_in[10];
    const float* beta = (const float*)d_in[11];
    float* out = (float*)d_out;
    unsigned char* wsb = (unsigned char*)d_ws;

    hipMemsetAsync(d_ws, 0, ZERO_BYTES, stream);
    prep_kernel<<<1, 512, 0, stream>>>(condraw, input, wsb);
    repack_kernel<<<2048, 256, 0, stream>>>(W0, W1, W2, wsb);
    lstm_persistent<<<NBLK, NTH, 0, stream>>>(input, b0, b1, b2, Wd, bd,
                                              gamma, beta, out, wsb);
}

// Round 2
// 25612.793 us; speedup vs baseline: 1.6652x; 1.6269x over previous
//
#include <hip/hip_runtime.h>
#include <math.h>

// Problem constants
#define B 64
#define T 512
#define F 256
#define U 1024
#define NBLK 256
#define NTH 512
#define WPAD 68   // zbuf row stride (floats): 68%32=4 -> conflict-free b128 partial stores

typedef unsigned short ushort_t;
typedef __attribute__((ext_vector_type(8))) _Float16 f16x8_t;  // MFMA A/B frag (4 VGPR)
typedef __attribute__((ext_vector_type(4))) float f32x4_t;     // MFMA C/D frag

// ---------------- workspace layout (BYTE offsets) ----------------
// Round-10: blocked state layouts so every write-through store is contiguous
// per block (drain fast, no HBM partial-line RMW amplification).
static const size_t OFF_STATS= 0;                  // fp32 [2 parity][64 b][8]: 4096
static const size_t OFF_COND = 4096;               // int[512]: 2048
static const size_t OFF_BAR  = 6144;               // int[320]: 1280
static const size_t OFF_H2B  = 7424;               // fp32 [256 ublk][64 b][4]: 262144
static const size_t OFF_HS   = 269568;             // f16 [2][3][256 ublk][64 b][4]: 786432
static const size_t OFF_XS   = 1056000;            // f16 [64 fblk][64 b][4]: 32768
static const size_t OFF_PW0  = 1088768;            // f16 [256 g][40 kt][512]: 10485760
static const size_t OFF_PW1  = 11574528;           // f16 [256][64][512]: 16777216
static const size_t OFF_PW2  = 28351744;           // f16 [256][64][512]: 16777216
static const size_t ZERO_BYTES = OFF_PW0;          // state region zeroed each launch
// bar int-offsets: counter=0 (monotonic, never reset); relay[i]=144+i*16
// (i<8, one 64B line each); minibar=272.

__device__ __forceinline__ float sigm(float x) {
    return 1.0f / (1.0f + __expf(-x));
}

__device__ __forceinline__ ushort_t f2h(float x) {   // RNE fp32->fp16
    _Float16 h = (_Float16)x;
    union { _Float16 h; ushort_t u; } v; v.h = h;
    return v.u;
}

// ---- write-through (device-coherent) stores: data lands at the coherence
// point, so consumers need NO release fence.
__device__ __forceinline__ void store_uc_u16(ushort_t* p, ushort_t v) {
    asm volatile("global_store_short %0, %1, off sc0 sc1"
                 :: "v"(p), "v"((unsigned)v) : "memory");
}
__device__ __forceinline__ void store_uc_f32(float* p, float v) {
    asm volatile("global_store_dword %0, %1, off sc0 sc1"
                 :: "v"(p), "v"(v) : "memory");
}
__device__ __forceinline__ void store_uc_b64(void* p, unsigned long long v) {
    asm volatile("global_store_dwordx2 %0, %1, off sc0 sc1"
                 :: "v"(p), "v"(v) : "memory");
}
__device__ __forceinline__ void drain_vmem() {
    asm volatile("s_waitcnt vmcnt(0)" ::: "memory");
}
// batched coherent-load fence: issue N asm loads, then this (rule #18)
__device__ __forceinline__ void wait_vm0() {
    asm volatile("s_waitcnt vmcnt(0)" ::: "memory");
    __builtin_amdgcn_sched_barrier(0);
}

// Round-10 barrier: single monotonic counter (cumulative arrivals = epoch*NBLK
// when all blocks reached epoch; no reset, no master level, no releaser
// drain). Last arriver publishes epoch to 8 relay lines (32 pollers/line).
// Freshness: atomic agent-scope ops are device-coherent; no inv needed.
__device__ __forceinline__ void phase_sync(int* bar, int epoch, int g) {
    drain_vmem();        // each wave drains its own write-through stores
    __syncthreads();
    if (threadIdx.x == 0) {
        const int prev = __hip_atomic_fetch_add(bar, 1, __ATOMIC_RELAXED,
                                                __HIP_MEMORY_SCOPE_AGENT);
        if (prev == epoch * NBLK - 1) {
            #pragma unroll
            for (int i = 0; i < 8; ++i)
                __hip_atomic_store(bar + 144 + i * 16, epoch, __ATOMIC_RELAXED,
                                   __HIP_MEMORY_SCOPE_AGENT);
        }
        int* myrelay = bar + 144 + (g & 7) * 16;
        int spins = 0;
        while (__hip_atomic_load(myrelay, __ATOMIC_RELAXED,
                                 __HIP_MEMORY_SCOPE_AGENT) < epoch) {
            __builtin_amdgcn_s_sleep(2);
            if ((++spins & 63) == 0)
                (void)__hip_atomic_load(myrelay, __ATOMIC_ACQUIRE,
                                        __HIP_MEMORY_SCOPE_AGENT);
        }
    }
    __syncthreads();
}

// Prep: decode conditioned_lst (bool-u8 vs int32 sniff), init f16 xs (blocked).
__global__ void prep_kernel(const unsigned char* __restrict__ condraw,
                            const float* __restrict__ input,
                            unsigned char* __restrict__ wsb) {
    __shared__ int s_not_int32;
    const int tid = threadIdx.x;
    if (tid == 0) s_not_int32 = 0;
    __syncthreads();
    if (tid < 512 && (tid & 3) != 0) {
        if (condraw[tid] != 0) s_not_int32 = 1;
    }
    __syncthreads();
    const int is32 = (s_not_int32 == 0);
    int* condw = (int*)(wsb + OFF_COND);
    if (tid < 512) {
        int cv = is32 ? ((const int*)condraw)[tid] : (int)condraw[tid];
        condw[tid] = (cv != 0) ? 1 : 0;
    }
    ushort_t* xs = (ushort_t*)(wsb + OFF_XS);
    for (int i = tid; i < B * F; i += blockDim.x) {
        const int b = i >> 8, f = i & 255;
        xs[(size_t)(((f >> 2) << 6) + b) * 4 + (f & 3)] =
            f2h(input[(size_t)b * (T * F) + f]);
    }
}

// Repack fp32 weights -> fp16 in MFMA B-fragment order (unchanged):
// PW_l[((g*KT + kt)*64 + L)*8 + j] = W_l[k][col], k = kt*32 + (L>>4)*8 + j,
// n = L&15, col = (n>>2)*1024 + g*4 + (n&3)
__global__ void repack_kernel(const float* __restrict__ W0,
                              const float* __restrict__ W1,
                              const float* __restrict__ W2,
                              unsigned char* __restrict__ wsb) {
    ushort_t* P0 = (ushort_t*)(wsb + OFF_PW0);
    ushort_t* P1 = (ushort_t*)(wsb + OFF_PW1);
    ushort_t* P2 = (ushort_t*)(wsb + OFF_PW2);
    const size_t stride = (size_t)gridDim.x * blockDim.x;
    const size_t tid = (size_t)blockIdx.x * blockDim.x + threadIdx.x;
    const size_t N0 = (size_t)256 * 40 * 512;
    const size_t N12 = (size_t)256 * 64 * 512;
    for (size_t i = tid; i < N0; i += stride) {
        const int g = (int)(i / 20480);
        const int r = (int)(i % 20480);
        const int kt = r >> 9, s = r & 511, L = s >> 3, j = s & 7;
        const int k = kt * 32 + ((L >> 4) << 3) + j;
        const int n = L & 15;
        const int col = ((n >> 2) << 10) + (g << 2) + (n & 3);
        P0[i] = f2h(W0[(size_t)k * 4096 + col]);
    }
    for (size_t i = tid; i < N12; i += stride) {
        const int g = (int)(i / 32768);
        const int r = (int)(i % 32768);
        const int kt = r >> 9, s = r & 511, L = s >> 3, j = s & 7;
        const int k = kt * 32 + ((L >> 4) << 3) + j;
        const int n = L & 15;
        const int col = ((n >> 2) << 10) + (g << 2) + (n & 3);
        const size_t src = (size_t)k * 4096 + col;
        P1[i] = f2h(W1[src]);
        P2[i] = f2h(W2[src]);
    }
}

__global__ void __launch_bounds__(NTH, 2)
lstm_persistent(const float* __restrict__ input,
                const float* __restrict__ b0, const float* __restrict__ b1,
                const float* __restrict__ b2,
                const float* __restrict__ Wd, const float* __restrict__ bd,
                const float* __restrict__ gamma, const float* __restrict__ beta,
                float* __restrict__ out, unsigned char* __restrict__ wsb) {
    const int g = blockIdx.x;
    const int tid = threadIdx.x;
    const int lane = tid & 63;
    const int wv = __builtin_amdgcn_readfirstlane(tid >> 6);  // 0..7
    const int ln15 = lane & 15;
    const int quad = lane >> 4;

    float* h2b = (float*)(wsb + OFF_H2B);          // fp32 [256 ublk][64 b][4]
    float* stats = (float*)(wsb + OFF_STATS);      // fp32 [2][64][8]
    int* bar = (int*)(wsb + OFF_BAR);
    ushort_t* hs = (ushort_t*)(wsb + OFF_HS);      // f16 [2][3][256][64][4]
    ushort_t* xs = (ushort_t*)(wsb + OFF_XS);      // f16 [64][64][4]
    const size_t HSZ = (size_t)256 * 64 * 4;       // ushorts per [parity][layer] tile

    __shared__ f16x8_t lds_pw0[40 * 64];     // 40 KB: L0 B-frags
    __shared__ f32x4_t lds_wd4[1024];        // 16 KB: Wd cols (g<64)
    __shared__ float zbuf[128 * WPAD];       // 34.8 KB
    __shared__ int lds_cond[512];            // 2 KB

    const int u0 = g << 2;
    const int f0 = g << 2;

    // B-frags in regs: Bw[0..3] = x-part kts (4wv+c); Bw[4..7] = h-part
    // kts (32+4wv+c).
    f16x8_t Bw1[8], Bw2[8];
    {
        const ushort_t* p1 = (const ushort_t*)(wsb + OFF_PW1) +
                             (size_t)g * 64 * 512 + (size_t)lane * 8;
        const ushort_t* p2 = (const ushort_t*)(wsb + OFF_PW2) +
                             (size_t)g * 64 * 512 + (size_t)lane * 8;
        #pragma unroll
        for (int i = 0; i < 4; ++i) {
            Bw1[i]     = *(const f16x8_t*)(p1 + (size_t)((wv << 2) + i) * 512);
            Bw1[4 + i] = *(const f16x8_t*)(p1 + (size_t)(32 + (wv << 2) + i) * 512);
            Bw2[i]     = *(const f16x8_t*)(p2 + (size_t)((wv << 2) + i) * 512);
            Bw2[4 + i] = *(const f16x8_t*)(p2 + (size_t)(32 + (wv << 2) + i) * 512);
        }
    }
    {
        const f16x8_t* src = (const f16x8_t*)((const ushort_t*)(wsb + OFF_PW0) +
                                              (size_t)g * 40 * 512);
        for (int i = tid; i < 40 * 64; i += NTH) lds_pw0[i] = src[i];
    }
    if (g < 64) {
        for (int k = tid; k < 1024; k += NTH)
            lds_wd4[k] = *(const f32x4_t*)(Wd + (size_t)k * F + f0);
    }
    for (int i = tid; i < 512; i += NTH) lds_cond[i] = ((const int*)(wsb + OFF_COND))[i];

    const int eb = tid & 63;
    const int eu = (tid >> 6) & 3;

    float bias0[4], bias1[4], bias2[4];
    if (tid < 256) {
        #pragma unroll
        for (int q = 0; q < 4; ++q) {
            bias0[q] = b0[(q << 10) + u0 + eu];
            bias1[q] = b1[(q << 10) + u0 + eu];
            bias2[q] = b2[(q << 10) + u0 + eu];
        }
    }
    float4 gm4 = {0,0,0,0}, bt4 = {0,0,0,0}, bd4 = {0,0,0,0};
    if (g < 64 && wv == 0) {
        gm4 = *(const float4*)(gamma + f0);
        bt4 = *(const float4*)(beta + f0);
        bd4 = *(const float4*)(bd + f0);
    }
    __syncthreads();

    float creg0 = 0.f, creg1 = 0.f, creg2 = 0.f;

    // Persistent accumulators: on entry to layer l's x-phase, accN holds the
    // h-recurrence partial for the CURRENT step (zero at t=0).
    f32x4_t acc0[4], acc1[4], acc2[4];
    #pragma unroll
    for (int mt = 0; mt < 4; ++mt) {
        acc0[mt] = (f32x4_t){0.f, 0.f, 0.f, 0.f};
        acc1[mt] = (f32x4_t){0.f, 0.f, 0.f, 0.f};
        acc2[mt] = (f32x4_t){0.f, 0.f, 0.f, 0.f};
    }

    // 4-kt MFMA slab over a blocked [256 ublk][64 b][4] f16 tile. Per lane:
    // rows ln15+16mt, k = (4wv+c)*32 + quad*8 + 0..7 -> two b64 coherent loads
    // at ublk ((4wv+c)*8 + 2quad) and +1. Batched issue, one vmcnt wait.
    auto mm4 = [&](f32x4_t (&acc)[4], const ushort_t* base,
                   const f16x8_t (&Bw)[8], const int boff) {
        unsigned long long lo[16], hi[16];
        const char* bb = (const char*)base + (size_t)ln15 * 8 +
                         (size_t)(quad << 1) * 512;
        #pragma unroll
        for (int c = 0; c < 4; ++c) {
            const char* pc = bb + (size_t)((wv << 2) + c) * 4096;
            #pragma unroll
            for (int mt = 0; mt < 4; ++mt) {
                asm volatile("global_load_dwordx2 %0, %1, off sc0 sc1"
                             : "=v"(lo[c * 4 + mt]) : "v"(pc + mt * 128));
                asm volatile("global_load_dwordx2 %0, %1, off sc0 sc1"
                             : "=v"(hi[c * 4 + mt]) : "v"(pc + mt * 128 + 512));
            }
        }
        wait_vm0();
        #pragma unroll
        for (int c = 0; c < 4; ++c) {
            #pragma unroll
            for (int mt = 0; mt < 4; ++mt) {
                union { unsigned long long q[2]; f16x8_t v; } u;
                u.q[0] = lo[c * 4 + mt]; u.q[1] = hi[c * 4 + mt];
                acc[mt] = __builtin_amdgcn_mfma_f32_16x16x32_f16(
                    u.v, Bw[boff + c], acc[mt], 0, 0, 0);
            }
        }
    };

    // L0 h-part: kts 8+4wv+c, B-frags from LDS.
    auto mm_h0 = [&](f32x4_t (&acc)[4], const ushort_t* base) {
        unsigned long long lo[16], hi[16];
        const char* bb = (const char*)base + (size_t)ln15 * 8 +
                         (size_t)(quad << 1) * 512;
        #pragma unroll
        for (int c = 0; c < 4; ++c) {
            const char* pc = bb + (size_t)((wv << 2) + c) * 4096;
            #pragma unroll
            for (int mt = 0; mt < 4; ++mt) {
                asm volatile("global_load_dwordx2 %0, %1, off sc0 sc1"
                             : "=v"(lo[c * 4 + mt]) : "v"(pc + mt * 128));
                asm volatile("global_load_dwordx2 %0, %1, off sc0 sc1"
                             : "=v"(hi[c * 4 + mt]) : "v"(pc + mt * 128 + 512));
            }
        }
        wait_vm0();
        #pragma unroll
        for (int c = 0; c < 4; ++c) {
            const f16x8_t Bb = lds_pw0[(8 + (wv << 2) + c) * 64 + lane];
            #pragma unroll
            for (int mt = 0; mt < 4; ++mt) {
                union { unsigned long long q[2]; f16x8_t v; } u;
                u.q[0] = lo[c * 4 + mt]; u.q[1] = hi[c * 4 + mt];
                acc[mt] = __builtin_amdgcn_mfma_f32_16x16x32_f16(
                    u.v, Bb, acc[mt], 0, 0, 0);
            }
        }
    };

    // dump acc -> zbuf, zero acc, 8-wave reduce + gates + coalesced h store.
    auto epilogue = [&](f32x4_t (&acc)[4], const float (&bi)[4], float& cr,
                        ushort_t* hdst, float* h2dst) {
        __syncthreads();
        {
            float* zrow = zbuf + (size_t)(wv * 16 + ln15) * WPAD;
            #pragma unroll
            for (int mt = 0; mt < 4; ++mt)
                *(f32x4_t*)(zrow + mt * 16 + (quad << 2)) = acc[mt];
            #pragma unroll
            for (int mt = 0; mt < 4; ++mt) acc[mt] = (f32x4_t){0.f, 0.f, 0.f, 0.f};
        }
        __syncthreads();
        if (tid < 256) {   // gate epilogue: (b=eb, unit u0+eu)
            float z[4];
            #pragma unroll
            for (int q = 0; q < 4; ++q) {
                float s = bi[q];
                #pragma unroll
                for (int w = 0; w < 8; ++w)
                    s += zbuf[(size_t)(w * 16 + q * 4 + eu) * WPAD + eb];
                z[q] = s;
            }
            const float ig = sigm(z[0]);
            const float gg = tanhf(z[1]);
            const float fg = sigm(z[2] + 1.0f);   // forget_bias = 1.0
            const float og = sigm(z[3]);
            const float cn = cr * fg + ig * gg;
            const float hn = og * tanhf(cn);
            cr = cn;
            // blocked layouts: block writes ONE contiguous 512B (hs) /
            // 1KB (h2b) region -> write-through drains in ~1 RT.
            store_uc_u16(hdst + ((size_t)g * 64 + eb) * 4 + eu, f2h(hn));
            if (h2dst) store_uc_f32(h2dst + ((size_t)g * 64 + eb) * 4 + eu, hn);
        }
    };

    int epoch = 0;
    for (int t = 0; t < T; ++t) {
        const int p = t & 1;
        const int pn = p ^ 1;
        ushort_t* hs0n = hs + (size_t)(pn * 3 + 0) * HSZ;
        ushort_t* hs1n = hs + (size_t)(pn * 3 + 1) * HSZ;
        ushort_t* hs2n = hs + (size_t)(pn * 3 + 2) * HSZ;

        // ---- phase 0: deferred h-prefetch (dense blocks) + L0 fresh-x ----
        if (g < 64) {
            // balance: dense blocks do their L1/L2 h-prefetch here (light
            // phase) instead of phase 3 (their heavy phase). Reads h1_{t-1},
            // h2_{t-1} = parity p tiles; zero-filled at t=0.
            mm4(acc1, hs + (size_t)(p * 3 + 1) * HSZ, Bw1, 4);
            mm4(acc2, hs + (size_t)(p * 3 + 2) * HSZ, Bw2, 4);
        }
        {
            unsigned long long xl[4], xh[4];
            const char* bb = (const char*)xs + (size_t)ln15 * 8 +
                             (size_t)(quad << 1) * 512 + (size_t)wv * 4096;
            #pragma unroll
            for (int mt = 0; mt < 4; ++mt) {
                asm volatile("global_load_dwordx2 %0, %1, off sc0 sc1"
                             : "=v"(xl[mt]) : "v"(bb + mt * 128));
                asm volatile("global_load_dwordx2 %0, %1, off sc0 sc1"
                             : "=v"(xh[mt]) : "v"(bb + mt * 128 + 512));
            }
            wait_vm0();
            const f16x8_t Bb = lds_pw0[wv * 64 + lane];
            #pragma unroll
            for (int mt = 0; mt < 4; ++mt) {
                union { unsigned long long q[2]; f16x8_t v; } u;
                u.q[0] = xl[mt]; u.q[1] = xh[mt];
                acc0[mt] = __builtin_amdgcn_mfma_f32_16x16x32_f16(
                    u.v, Bb, acc0[mt], 0, 0, 0);
            }
        }
        epilogue(acc0, bias0, creg0, hs0n, nullptr);
        phase_sync(bar, ++epoch, g);

        // ---- phase 1: L1 fresh-x half (A = h0_t) ----
        mm4(acc1, hs0n, Bw1, 0);
        epilogue(acc1, bias1, creg1, hs1n, nullptr);
        phase_sync(bar, ++epoch, g);

        // ---- phase 2: L2 fresh-x half (A = h1_t) ----
        mm4(acc2, hs1n, Bw2, 0);
        epilogue(acc2, bias2, creg2, hs2n, h2b);
        phase_sync(bar, ++epoch, g);

        // ------- phase 3: dense + LN (g<64) overlapped with h-prefetch -------
        if (g < 64) {
            float accd[4] = {0.f, 0.f, 0.f, 0.f};
            // wave wv: k = wv*128..+127; blocked h2b -> 32 coherent dwordx4
            #pragma unroll
            for (int half = 0; half < 2; ++half) {
                f32x4_t hv[16];
                const char* hbb = (const char*)h2b +
                    (((size_t)(wv * 32 + half * 16) * 64) + lane) * 16;
                #pragma unroll
                for (int i = 0; i < 16; ++i)
                    asm volatile("global_load_dwordx4 %0, %1, off sc0 sc1"
                                 : "=v"(hv[i]) : "v"(hbb + (size_t)i * 1024));
                wait_vm0();
                #pragma unroll
                for (int i = 0; i < 16; ++i) {
                    const int k = (wv << 7) + (half << 6) + (i << 2);
                    #pragma unroll
                    for (int j = 0; j < 4; ++j) {
                        const f32x4_t w4 = lds_wd4[k + j];
                        accd[0] = fmaf(w4[0], hv[i][j], accd[0]);
                        accd[1] = fmaf(w4[1], hv[i][j], accd[1]);
                        accd[2] = fmaf(w4[2], hv[i][j], accd[2]);
                        accd[3] = fmaf(w4[3], hv[i][j], accd[3]);
                    }
                }
            }
            __syncthreads();
            #pragma unroll
            for (int jj = 0; jj < 4; ++jj)
                zbuf[(size_t)(wv * 16 + jj) * WPAD + lane] = accd[jj];
            __syncthreads();
            if (wv == 0) {
                float yv[4];
                float s = 0.f, ss = 0.f;
                #pragma unroll
                for (int jj = 0; jj < 4; ++jj) {
                    float y = 0.f;
                    #pragma unroll
                    for (int w = 0; w < 8; ++w)
                        y += zbuf[(size_t)(w * 16 + jj) * WPAD + lane];
                    y += (jj == 0) ? bd4.x : (jj == 1) ? bd4.y : (jj == 2) ? bd4.z : bd4.w;
                    yv[jj] = y;
                    s += y;
                    ss += y * y;
                }
                // padded stats: one 32B row per batch -> 2 rows/line,
                // ~256 RMWs/line instead of ~1000.
                float* st = stats + (size_t)p * (64 * 8);
                atomicAdd(&st[(size_t)lane * 8], s);
                atomicAdd(&st[(size_t)lane * 8 + 1], ss);
                if (lane == 0) {
                    drain_vmem();   // wave-wide: stats adds complete
                    __hip_atomic_fetch_add(bar + 272, 1, __ATOMIC_RELAXED,
                                           __HIP_MEMORY_SCOPE_AGENT);
                    const int target = (t + 1) * 64;
                    int spins = 0;
                    while (__hip_atomic_load(bar + 272, __ATOMIC_RELAXED,
                                             __HIP_MEMORY_SCOPE_AGENT) < target) {
                        __builtin_amdgcn_s_sleep(2);
                        if ((++spins & 63) == 0)
                            (void)__hip_atomic_load(bar + 272, __ATOMIC_ACQUIRE,
                                                    __HIP_MEMORY_SCOPE_AGENT);
                    }
                }
                union { unsigned long long u64; float f[2]; } sv;
                asm volatile("global_load_dwordx2 %0, %1, off sc0 sc1"
                             : "=v"(sv.u64) : "v"(st + (size_t)lane * 8));
                wait_vm0();
                const float mu = sv.f[0] * (1.0f / F);
                const float var = sv.f[1] * (1.0f / F) - mu * mu;
                const float rs = rsqrtf(var + 1e-12f);
                float em[4];
                em[0] = fmaxf((yv[0] - mu) * rs * gm4.x + bt4.x, 0.0f);
                em[1] = fmaxf((yv[1] - mu) * rs * gm4.y + bt4.y, 0.0f);
                em[2] = fmaxf((yv[2] - mu) * rs * gm4.z + bt4.z, 0.0f);
                em[3] = fmaxf((yv[3] - mu) * rs * gm4.w + bt4.w, 0.0f);
                *(float4*)(out + (size_t)lane * (T * F) + (size_t)t * F + f0) =
                    make_float4(em[0], em[1], em[2], em[3]);
                if (t + 1 < T) {
                    float xn[4];
                    if (lds_cond[t + 1] != 0) {
                        const float4 iv = *(const float4*)(input + (size_t)lane * (T * F) +
                                                           (size_t)(t + 1) * F + f0);
                        xn[0] = iv.x; xn[1] = iv.y; xn[2] = iv.z; xn[3] = iv.w;
                    } else {
                        xn[0] = em[0]; xn[1] = em[1]; xn[2] = em[2]; xn[3] = em[3];
                    }
                    unsigned long long pk =
                        (unsigned long long)f2h(xn[0]) |
                        ((unsigned long long)f2h(xn[1]) << 16) |
                        ((unsigned long long)f2h(xn[2]) << 32) |
                        ((unsigned long long)f2h(xn[3]) << 48);
                    // blocked xs: block writes contiguous 512B
                    store_uc_b64(xs + ((size_t)g * 64 + lane) * 4, pk);
                }
            }
        } else if (g == 64 && wv == 0) {
            // zero other-parity stats for step t+1 (one 8B store per lane)
            float* st2 = stats + (size_t)pn * (64 * 8);
            store_uc_b64(&st2[(size_t)lane * 8], 0ULL);
        }

        // h-recurrence prefetch for step t+1: L0 by everyone; L1/L2 only by
        // non-dense blocks (dense blocks defer theirs to next phase 0).
        if (t + 1 < T) {
            mm_h0(acc0, hs0n);               // L0: kt 8+4wv+c   <- h0_t
            if (g >= 64) {
                mm4(acc1, hs1n, Bw1, 4);     // L1: kt 32+4wv+c  <- h1_t
                mm4(acc2, hs2n, Bw2, 4);     // L2: kt 32+4wv+c  <- h2_t
            }
        }
        phase_sync(bar, ++epoch, g);
    }
}

extern "C" void kernel_launch(void* const* d_in, const int* in_sizes, int n_in,
                              void* d_out, int out_size, void* d_ws, size_t ws_size,
                              hipStream_t stream) {
    const float* input = (const float*)d_in[0];
    const unsigned char* condraw = (const unsigned char*)d_in[1];
    const float* W0 = (const float*)d_in[2];
    const float* b0 = (const float*)d_in[3];
    const float* W1 = (const float*)d_in[4];
    const float* b1 = (const float*)d_in[5];
    const float* W2 = (const float*)d_in[6];
    const float* b2 = (const float*)d_in[7];
    const float* Wd = (const float*)d_in[8];
    const float* bd = (const float*)d_in[9];
    const float* gamma = (const float*)d_in[10];
    const float* beta = (const float*)d_in[11];
    float* out = (float*)d_out;
    unsigned char* wsb = (unsigned char*)d_ws;

    hipMemsetAsync(d_ws, 0, ZERO_BYTES, stream);
    prep_kernel<<<1, 512, 0, stream>>>(condraw, input, wsb);
    repack_kernel<<<2048, 256, 0, stream>>>(W0, W1, W2, wsb);
    lstm_persistent<<<NBLK, NTH, 0, stream>>>(input, b0, b1, b2, Wd, bd,
                                              gamma, beta, out, wsb);
}

// Round 4
// 24145.117 us; speedup vs baseline: 1.7664x; 1.0608x over previous
//
#include <hip/hip_runtime.h>
#include <math.h>

// Problem constants
#define B 64
#define T 512
#define F 256
#define U 1024
#define NBLK 256
#define NTH 512
#define WPAD 68   // zbuf row stride (floats): 68%32=4 -> conflict-free b128 partial stores

typedef unsigned short ushort_t;
typedef __attribute__((ext_vector_type(8))) _Float16 f16x8_t;  // MFMA A/B frag (4 VGPR)
typedef __attribute__((ext_vector_type(4))) float f32x4_t;     // MFMA C/D frag

// ---------------- workspace layout (BYTE offsets) ----------------
// Blocked state layouts: every write-through store is contiguous per block.
static const size_t OFF_STATS= 0;                  // fp32 [2 parity][64 b][8]: 4096
static const size_t OFF_COND = 4096;               // int[512]: 2048
static const size_t OFF_BAR  = 6144;               // int[320]: 1280
static const size_t OFF_H2B  = 7424;               // fp32 [256 ublk][64 b][4]: 262144
static const size_t OFF_HS   = 269568;             // f16 [2][3][256 ublk][64 b][4]: 786432
static const size_t OFF_XS   = 1056000;            // f16 [64 fblk][64 b][4]: 32768
static const size_t OFF_PW0  = 1088768;            // f16 [256 g][40 kt][512]: 10485760
static const size_t OFF_PW1  = 11574528;           // f16 [256][64][512]: 16777216
static const size_t OFF_PW2  = 28351744;           // f16 [256][64][512]: 16777216
static const size_t ZERO_BYTES = OFF_PW0;          // state region zeroed each launch
// bar int-offsets: sub[i]=i*16 (i<8, monotonic, never reset); master=128;
// relay[i]=144+i*16; minibar=272.

__device__ __forceinline__ float sigm(float x) {
    return 1.0f / (1.0f + __expf(-x));
}

__device__ __forceinline__ ushort_t f2h(float x) {   // RNE fp32->fp16
    _Float16 h = (_Float16)x;
    union { _Float16 h; ushort_t u; } v; v.h = h;
    return v.u;
}

// ---- write-through (device-coherent) stores: data lands at the coherence
// point, so consumers need NO release fence. Consumers use PLAIN loads +
// the once-per-step acquire inv (first-touch-since-inv => fresh).
__device__ __forceinline__ void store_uc_u16(ushort_t* p, ushort_t v) {
    asm volatile("global_store_short %0, %1, off sc0 sc1"
                 :: "v"(p), "v"((unsigned)v) : "memory");
}
__device__ __forceinline__ void store_uc_f32(float* p, float v) {
    asm volatile("global_store_dword %0, %1, off sc0 sc1"
                 :: "v"(p), "v"(v) : "memory");
}
__device__ __forceinline__ void store_uc_b64(void* p, unsigned long long v) {
    asm volatile("global_store_dwordx2 %0, %1, off sc0 sc1"
                 :: "v"(p), "v"(v) : "memory");
}
__device__ __forceinline__ void drain_vmem() {
    asm volatile("s_waitcnt vmcnt(0)" ::: "memory");
}
__device__ __forceinline__ void wait_vm0() {
    asm volatile("s_waitcnt vmcnt(0)" ::: "memory");
    __builtin_amdgcn_sched_barrier(0);
}

// Hierarchical MONOTONIC barrier: 8 sub-lines x 32 arrivals (parallel RMW
// streams, ~32 serialized RMWs/line instead of 256), master line, 8 relay
// lines (32 pollers each). Cumulative counters -> no reset, no releaser
// drain. Producers drained their write-through stores before arriving, so
// relay-epoch observation implies state is at the coherence point.
__device__ __forceinline__ void phase_sync(int* bar, int epoch, int g) {
    drain_vmem();        // own write-through stores reach coherence point
    __syncthreads();
    if (threadIdx.x == 0) {
        const int sub = g & 7;
        const int prev = __hip_atomic_fetch_add(bar + sub * 16, 1,
                                                __ATOMIC_RELAXED, __HIP_MEMORY_SCOPE_AGENT);
        if (prev == epoch * 32 - 1) {
            const int pm = __hip_atomic_fetch_add(bar + 128, 1,
                                                  __ATOMIC_RELAXED, __HIP_MEMORY_SCOPE_AGENT);
            if (pm == epoch * 8 - 1) {
                #pragma unroll
                for (int i = 0; i < 8; ++i)
                    __hip_atomic_store(bar + 144 + i * 16, epoch, __ATOMIC_RELAXED,
                                       __HIP_MEMORY_SCOPE_AGENT);
            }
        }
        int* myrelay = bar + 144 + sub * 16;
        int spins = 0;
        while (__hip_atomic_load(myrelay, __ATOMIC_RELAXED,
                                 __HIP_MEMORY_SCOPE_AGENT) < epoch) {
            __builtin_amdgcn_s_sleep(2);
            if ((++spins & 63) == 0)
                (void)__hip_atomic_load(myrelay, __ATOMIC_ACQUIRE,
                                        __HIP_MEMORY_SCOPE_AGENT);
        }
    }
    __syncthreads();
}

// Prep: decode conditioned_lst (bool-u8 vs int32 sniff), init f16 xs (blocked).
__global__ void prep_kernel(const unsigned char* __restrict__ condraw,
                            const float* __restrict__ input,
                            unsigned char* __restrict__ wsb) {
    __shared__ int s_not_int32;
    const int tid = threadIdx.x;
    if (tid == 0) s_not_int32 = 0;
    __syncthreads();
    if (tid < 512 && (tid & 3) != 0) {
        if (condraw[tid] != 0) s_not_int32 = 1;
    }
    __syncthreads();
    const int is32 = (s_not_int32 == 0);
    int* condw = (int*)(wsb + OFF_COND);
    if (tid < 512) {
        int cv = is32 ? ((const int*)condraw)[tid] : (int)condraw[tid];
        condw[tid] = (cv != 0) ? 1 : 0;
    }
    ushort_t* xs = (ushort_t*)(wsb + OFF_XS);
    for (int i = tid; i < B * F; i += blockDim.x) {
        const int b = i >> 8, f = i & 255;
        xs[(size_t)(((f >> 2) << 6) + b) * 4 + (f & 3)] =
            f2h(input[(size_t)b * (T * F) + f]);
    }
}

// Repack fp32 weights -> fp16 in MFMA B-fragment order (unchanged):
// PW_l[((g*KT + kt)*64 + L)*8 + j] = W_l[k][col], k = kt*32 + (L>>4)*8 + j,
// n = L&15, col = (n>>2)*1024 + g*4 + (n&3)
__global__ void repack_kernel(const float* __restrict__ W0,
                              const float* __restrict__ W1,
                              const float* __restrict__ W2,
                              unsigned char* __restrict__ wsb) {
    ushort_t* P0 = (ushort_t*)(wsb + OFF_PW0);
    ushort_t* P1 = (ushort_t*)(wsb + OFF_PW1);
    ushort_t* P2 = (ushort_t*)(wsb + OFF_PW2);
    const size_t stride = (size_t)gridDim.x * blockDim.x;
    const size_t tid = (size_t)blockIdx.x * blockDim.x + threadIdx.x;
    const size_t N0 = (size_t)256 * 40 * 512;
    const size_t N12 = (size_t)256 * 64 * 512;
    for (size_t i = tid; i < N0; i += stride) {
        const int g = (int)(i / 20480);
        const int r = (int)(i % 20480);
        const int kt = r >> 9, s = r & 511, L = s >> 3, j = s & 7;
        const int k = kt * 32 + ((L >> 4) << 3) + j;
        const int n = L & 15;
        const int col = ((n >> 2) << 10) + (g << 2) + (n & 3);
        P0[i] = f2h(W0[(size_t)k * 4096 + col]);
    }
    for (size_t i = tid; i < N12; i += stride) {
        const int g = (int)(i / 32768);
        const int r = (int)(i % 32768);
        const int kt = r >> 9, s = r & 511, L = s >> 3, j = s & 7;
        const int k = kt * 32 + ((L >> 4) << 3) + j;
        const int n = L & 15;
        const int col = ((n >> 2) << 10) + (g << 2) + (n & 3);
        const size_t src = (size_t)k * 4096 + col;
        P1[i] = f2h(W1[src]);
        P2[i] = f2h(W2[src]);
    }
}

__global__ void __launch_bounds__(NTH, 2)
lstm_persistent(const float* __restrict__ input,
                const float* __restrict__ b0, const float* __restrict__ b1,
                const float* __restrict__ b2,
                const float* __restrict__ Wd, const float* __restrict__ bd,
                const float* __restrict__ gamma, const float* __restrict__ beta,
                float* __restrict__ out, unsigned char* __restrict__ wsb) {
    const int g = blockIdx.x;
    const int tid = threadIdx.x;
    const int lane = tid & 63;
    const int wv = __builtin_amdgcn_readfirstlane(tid >> 6);  // 0..7
    const int ln15 = lane & 15;
    const int quad = lane >> 4;

    float* h2b = (float*)(wsb + OFF_H2B);          // fp32 [256 ublk][64 b][4]
    float* stats = (float*)(wsb + OFF_STATS);      // fp32 [2][64][8]
    int* bar = (int*)(wsb + OFF_BAR);
    ushort_t* hs = (ushort_t*)(wsb + OFF_HS);      // f16 [2][3][256][64][4]
    ushort_t* xs = (ushort_t*)(wsb + OFF_XS);      // f16 [64][64][4]
    const size_t HSZ = (size_t)256 * 64 * 4;       // ushorts per [parity][layer] tile

    __shared__ f16x8_t lds_pw0[40 * 64];     // 40 KB: L0 B-frags
    __shared__ f32x4_t lds_wd4[1024];        // 16 KB: Wd cols (g<64)
    __shared__ float zbuf[128 * WPAD];       // 34.8 KB
    __shared__ int lds_cond[512];            // 2 KB

    const int u0 = g << 2;
    const int f0 = g << 2;

    // B-frags in regs: Bw[0..3] = x-part kts (4wv+c); Bw[4..7] = h-part
    // kts (32+4wv+c).
    f16x8_t Bw1[8], Bw2[8];
    {
        const ushort_t* p1 = (const ushort_t*)(wsb + OFF_PW1) +
                             (size_t)g * 64 * 512 + (size_t)lane * 8;
        const ushort_t* p2 = (const ushort_t*)(wsb + OFF_PW2) +
                             (size_t)g * 64 * 512 + (size_t)lane * 8;
        #pragma unroll
        for (int i = 0; i < 4; ++i) {
            Bw1[i]     = *(const f16x8_t*)(p1 + (size_t)((wv << 2) + i) * 512);
            Bw1[4 + i] = *(const f16x8_t*)(p1 + (size_t)(32 + (wv << 2) + i) * 512);
            Bw2[i]     = *(const f16x8_t*)(p2 + (size_t)((wv << 2) + i) * 512);
            Bw2[4 + i] = *(const f16x8_t*)(p2 + (size_t)(32 + (wv << 2) + i) * 512);
        }
    }
    {
        const f16x8_t* src = (const f16x8_t*)((const ushort_t*)(wsb + OFF_PW0) +
                                              (size_t)g * 40 * 512);
        for (int i = tid; i < 40 * 64; i += NTH) lds_pw0[i] = src[i];
    }
    if (g < 64) {
        for (int k = tid; k < 1024; k += NTH)
            lds_wd4[k] = *(const f32x4_t*)(Wd + (size_t)k * F + f0);
    }
    for (int i = tid; i < 512; i += NTH) lds_cond[i] = ((const int*)(wsb + OFF_COND))[i];

    const int eb = tid & 63;
    const int eu = (tid >> 6) & 3;

    float bias0[4], bias1[4], bias2[4];
    if (tid < 256) {
        #pragma unroll
        for (int q = 0; q < 4; ++q) {
            bias0[q] = b0[(q << 10) + u0 + eu];
            bias1[q] = b1[(q << 10) + u0 + eu];
            bias2[q] = b2[(q << 10) + u0 + eu];
        }
    }
    float4 gm4 = {0,0,0,0}, bt4 = {0,0,0,0}, bd4 = {0,0,0,0};
    if (g < 64 && wv == 0) {
        gm4 = *(const float4*)(gamma + f0);
        bt4 = *(const float4*)(beta + f0);
        bd4 = *(const float4*)(bd + f0);
    }
    __syncthreads();

    float creg0 = 0.f, creg1 = 0.f, creg2 = 0.f;

    // Persistent accumulators: on entry to layer l's x-phase, accN holds the
    // h-recurrence partial for the CURRENT step (zero at t=0).
    f32x4_t acc0[4], acc1[4], acc2[4];
    #pragma unroll
    for (int mt = 0; mt < 4; ++mt) {
        acc0[mt] = (f32x4_t){0.f, 0.f, 0.f, 0.f};
        acc1[mt] = (f32x4_t){0.f, 0.f, 0.f, 0.f};
        acc2[mt] = (f32x4_t){0.f, 0.f, 0.f, 0.f};
    }

    // plain-load A-fragment: two 8B chunks 512B apart (blocked layout)
    auto ld_frag = [&](const char* p) -> f16x8_t {
        union { unsigned long long q[2]; f16x8_t v; } u;
        u.q[0] = *(const unsigned long long*)(p);
        u.q[1] = *(const unsigned long long*)(p + 512);
        return u.v;
    };

    // 4-kt MFMA slab over a blocked [256 ublk][64 b][4] f16 tile, PLAIN
    // (cached) loads. Freshness: every call's lines are either first-touch
    // since this step's inv (fetch from coherence point) or were read
    // earlier THIS step with no intervening writes (valid cache hit).
    auto mm4 = [&](f32x4_t (&acc)[4], const ushort_t* base,
                   const f16x8_t (&Bw)[8], const int boff) {
        f16x8_t Ab[4][4];
        const char* bb = (const char*)base + (size_t)ln15 * 8 +
                         (size_t)(quad << 1) * 512;
        #pragma unroll
        for (int c = 0; c < 4; ++c) {
            const char* pc = bb + (size_t)((wv << 2) + c) * 4096;
            #pragma unroll
            for (int mt = 0; mt < 4; ++mt)
                Ab[c][mt] = ld_frag(pc + mt * 128);
        }
        #pragma unroll
        for (int c = 0; c < 4; ++c) {
            #pragma unroll
            for (int mt = 0; mt < 4; ++mt)
                acc[mt] = __builtin_amdgcn_mfma_f32_16x16x32_f16(
                    Ab[c][mt], Bw[boff + c], acc[mt], 0, 0, 0);
        }
    };

    // L0 h-part: kts 8+4wv+c. B-frag index uses kt (8+4wv+c); A-data column
    // is k - F = (4wv+c)*32 -> A ublk base (4wv+c)*4096.  [R3 bug was +8 here]
    auto mm_h0 = [&](f32x4_t (&acc)[4], const ushort_t* base) {
        f16x8_t Ab[4][4];
        const char* bb = (const char*)base + (size_t)ln15 * 8 +
                         (size_t)(quad << 1) * 512;
        #pragma unroll
        for (int c = 0; c < 4; ++c) {
            const char* pc = bb + (size_t)((wv << 2) + c) * 4096;
            #pragma unroll
            for (int mt = 0; mt < 4; ++mt)
                Ab[c][mt] = ld_frag(pc + mt * 128);
        }
        #pragma unroll
        for (int c = 0; c < 4; ++c) {
            const f16x8_t Bb = lds_pw0[(8 + (wv << 2) + c) * 64 + lane];
            #pragma unroll
            for (int mt = 0; mt < 4; ++mt)
                acc[mt] = __builtin_amdgcn_mfma_f32_16x16x32_f16(
                    Ab[c][mt], Bb, acc[mt], 0, 0, 0);
        }
    };

    // dump acc -> zbuf, zero acc, 8-wave reduce + gates + coalesced h store.
    auto epilogue = [&](f32x4_t (&acc)[4], const float (&bi)[4], float& cr,
                        ushort_t* hdst, float* h2dst) {
        __syncthreads();
        {
            float* zrow = zbuf + (size_t)(wv * 16 + ln15) * WPAD;
            #pragma unroll
            for (int mt = 0; mt < 4; ++mt)
                *(f32x4_t*)(zrow + mt * 16 + (quad << 2)) = acc[mt];
            #pragma unroll
            for (int mt = 0; mt < 4; ++mt) acc[mt] = (f32x4_t){0.f, 0.f, 0.f, 0.f};
        }
        __syncthreads();
        if (tid < 256) {   // gate epilogue: (b=eb, unit u0+eu)
            float z[4];
            #pragma unroll
            for (int q = 0; q < 4; ++q) {
                float s = bi[q];
                #pragma unroll
                for (int w = 0; w < 8; ++w)
                    s += zbuf[(size_t)(w * 16 + q * 4 + eu) * WPAD + eb];
                z[q] = s;
            }
            const float ig = sigm(z[0]);
            const float gg = tanhf(z[1]);
            const float fg = sigm(z[2] + 1.0f);   // forget_bias = 1.0
            const float og = sigm(z[3]);
            const float cn = cr * fg + ig * gg;
            const float hn = og * tanhf(cn);
            cr = cn;
            // blocked layouts: block writes ONE contiguous 512B (hs) /
            // 1KB (h2b) region -> write-through drains in ~1 RT.
            store_uc_u16(hdst + ((size_t)g * 64 + eb) * 4 + eu, f2h(hn));
            if (h2dst) store_uc_f32(h2dst + ((size_t)g * 64 + eb) * 4 + eu, hn);
        }
    };

    int epoch = 0;
    for (int t = 0; t < T; ++t) {
        const int p = t & 1;
        const int pn = p ^ 1;
        ushort_t* hs0n = hs + (size_t)(pn * 3 + 0) * HSZ;
        ushort_t* hs1n = hs + (size_t)(pn * 3 + 1) * HSZ;
        ushort_t* hs2n = hs + (size_t)(pn * 3 + 2) * HSZ;

        // THE one inv per step: wipes L1/L2 so this step's state reads are
        // first-touch-fresh; per-XCD L2 then absorbs the 256-block read
        // redundancy (32 blocks/XCD share each fetched state line).
        __builtin_amdgcn_fence(__ATOMIC_ACQUIRE, "agent");

        // ---- phase 0: deferred h-prefetch (dense blocks) + L0 fresh-x ----
        if (g < 64) {
            // dense blocks' L1/L2 h-prefetch here (their light phase).
            // Reads parity-p tiles written in step t-1 (fresh post-inv).
            mm4(acc1, hs + (size_t)(p * 3 + 1) * HSZ, Bw1, 4);
            mm4(acc2, hs + (size_t)(p * 3 + 2) * HSZ, Bw2, 4);
        }
        {
            // L0 x-part: kt = wv, from xs (written step t-1 P3; fresh).
            f16x8_t Ax[4];
            const char* bb = (const char*)xs + (size_t)ln15 * 8 +
                             (size_t)(quad << 1) * 512 + (size_t)wv * 4096;
            #pragma unroll
            for (int mt = 0; mt < 4; ++mt)
                Ax[mt] = ld_frag(bb + mt * 128);
            const f16x8_t Bb = lds_pw0[wv * 64 + lane];
            #pragma unroll
            for (int mt = 0; mt < 4; ++mt)
                acc0[mt] = __builtin_amdgcn_mfma_f32_16x16x32_f16(
                    Ax[mt], Bb, acc0[mt], 0, 0, 0);
        }
        epilogue(acc0, bias0, creg0, hs0n, nullptr);
        phase_sync(bar, ++epoch, g);

        // ---- phase 1: L1 fresh-x half (A = h0_t) + dense blocks' L0 h-pf ----
        mm4(acc1, hs0n, Bw1, 0);
        if (g < 64) mm_h0(acc0, hs0n);   // moved off dense blocks' P3
        epilogue(acc1, bias1, creg1, hs1n, nullptr);
        phase_sync(bar, ++epoch, g);

        // ---- phase 2: L2 fresh-x half (A = h1_t) ----
        mm4(acc2, hs1n, Bw2, 0);
        epilogue(acc2, bias2, creg2, hs2n, h2b);
        phase_sync(bar, ++epoch, g);

        // ------- phase 3: dense + LN (g<64) / h-prefetch (g>=64) -------
        if (g < 64) {
            float accd[4] = {0.f, 0.f, 0.f, 0.f};
            // wave wv: k = wv*128..+127; blocked h2b (written P2; fresh) ->
            // 32 cached dwordx4 per lane.
            #pragma unroll
            for (int half = 0; half < 2; ++half) {
                f32x4_t hv[16];
                const f32x4_t* hb4 = (const f32x4_t*)h2b +
                    (size_t)(wv * 32 + half * 16) * 64 + lane;
                #pragma unroll
                for (int i = 0; i < 16; ++i)
                    hv[i] = hb4[(size_t)i * 64];
                #pragma unroll
                for (int i = 0; i < 16; ++i) {
                    const int k = (wv << 7) + (half << 6) + (i << 2);
                    #pragma unroll
                    for (int j = 0; j < 4; ++j) {
                        const f32x4_t w4 = lds_wd4[k + j];
                        accd[0] = fmaf(w4[0], hv[i][j], accd[0]);
                        accd[1] = fmaf(w4[1], hv[i][j], accd[1]);
                        accd[2] = fmaf(w4[2], hv[i][j], accd[2]);
                        accd[3] = fmaf(w4[3], hv[i][j], accd[3]);
                    }
                }
            }
            __syncthreads();
            #pragma unroll
            for (int jj = 0; jj < 4; ++jj)
                zbuf[(size_t)(wv * 16 + jj) * WPAD + lane] = accd[jj];
            __syncthreads();
            if (wv == 0) {
                float yv[4];
                float s = 0.f, ss = 0.f;
                #pragma unroll
                for (int jj = 0; jj < 4; ++jj) {
                    float y = 0.f;
                    #pragma unroll
                    for (int w = 0; w < 8; ++w)
                        y += zbuf[(size_t)(w * 16 + jj) * WPAD + lane];
                    y += (jj == 0) ? bd4.x : (jj == 1) ? bd4.y : (jj == 2) ? bd4.z : bd4.w;
                    yv[jj] = y;
                    s += y;
                    ss += y * y;
                }
                // padded stats: one 32B row per batch (atomics at coherence pt)
                float* st = stats + (size_t)p * (64 * 8);
                atomicAdd(&st[(size_t)lane * 8], s);
                atomicAdd(&st[(size_t)lane * 8 + 1], ss);
                if (lane == 0) {
                    drain_vmem();   // wave-wide: stats adds complete
                    __hip_atomic_fetch_add(bar + 272, 1, __ATOMIC_RELAXED,
                                           __HIP_MEMORY_SCOPE_AGENT);
                    const int target = (t + 1) * 64;
                    int spins = 0;
                    while (__hip_atomic_load(bar + 272, __ATOMIC_RELAXED,
                                             __HIP_MEMORY_SCOPE_AGENT) < target) {
                        __builtin_amdgcn_s_sleep(2);
                        if ((++spins & 63) == 0)
                            (void)__hip_atomic_load(bar + 272, __ATOMIC_ACQUIRE,
                                                    __HIP_MEMORY_SCOPE_AGENT);
                    }
                }
                // coherent stats read (atomics bypass caches; 1 load, cheap)
                union { unsigned long long u64; float f[2]; } sv;
                asm volatile("global_load_dwordx2 %0, %1, off sc0 sc1"
                             : "=v"(sv.u64) : "v"(st + (size_t)lane * 8));
                wait_vm0();
                const float mu = sv.f[0] * (1.0f / F);
                const float var = sv.f[1] * (1.0f / F) - mu * mu;
                const float rs = rsqrtf(var + 1e-12f);
                float em[4];
                em[0] = fmaxf((yv[0] - mu) * rs * gm4.x + bt4.x, 0.0f);
                em[1] = fmaxf((yv[1] - mu) * rs * gm4.y + bt4.y, 0.0f);
                em[2] = fmaxf((yv[2] - mu) * rs * gm4.z + bt4.z, 0.0f);
                em[3] = fmaxf((yv[3] - mu) * rs * gm4.w + bt4.w, 0.0f);
                *(float4*)(out + (size_t)lane * (T * F) + (size_t)t * F + f0) =
                    make_float4(em[0], em[1], em[2], em[3]);
                if (t + 1 < T) {
                    float xn[4];
                    if (lds_cond[t + 1] != 0) {
                        const float4 iv = *(const float4*)(input + (size_t)lane * (T * F) +
                                                           (size_t)(t + 1) * F + f0);
                        xn[0] = iv.x; xn[1] = iv.y; xn[2] = iv.z; xn[3] = iv.w;
                    } else {
                        xn[0] = em[0]; xn[1] = em[1]; xn[2] = em[2]; xn[3] = em[3];
                    }
                    unsigned long long pk =
                        (unsigned long long)f2h(xn[0]) |
                        ((unsigned long long)f2h(xn[1]) << 16) |
                        ((unsigned long long)f2h(xn[2]) << 32) |
                        ((unsigned long long)f2h(xn[3]) << 48);
                    // blocked xs: block writes contiguous 512B
                    store_uc_b64(xs + ((size_t)g * 64 + lane) * 4, pk);
                }
            }
        } else if (g == 64 && wv == 0) {
            // zero other-parity stats for step t+1 (one 8B store per lane)
            float* st2 = stats + (size_t)pn * (64 * 8);
            store_uc_b64(&st2[(size_t)lane * 8], 0ULL);
        }

        // h-recurrence prefetch for step t+1: non-dense blocks only (dense
        // blocks deferred L1/L2 to next P0, L0 to P1).
        if (g >= 64 && t + 1 < T) {
            mm_h0(acc0, hs0n);               // L0: kt 8+4wv+c   <- h0_t (fresh)
            mm4(acc1, hs1n, Bw1, 4);         // L1: cached from P2 read, valid
            mm4(acc2, hs2n, Bw2, 4);         // L2: first touch, fresh
        }
        phase_sync(bar, ++epoch, g);
    }
}

extern "C" void kernel_launch(void* const* d_in, const int* in_sizes, int n_in,
                              void* d_out, int out_size, void* d_ws, size_t ws_size,
                              hipStream_t stream) {
    const float* input = (const float*)d_in[0];
    const unsigned char* condraw = (const unsigned char*)d_in[1];
    const float* W0 = (const float*)d_in[2];
    const float* b0 = (const float*)d_in[3];
    const float* W1 = (const float*)d_in[4];
    const float* b1 = (const float*)d_in[5];
    const float* W2 = (const float*)d_in[6];
    const float* b2 = (const float*)d_in[7];
    const float* Wd = (const float*)d_in[8];
    const float* bd = (const float*)d_in[9];
    const float* gamma = (const float*)d_in[10];
    const float* beta = (const float*)d_in[11];
    float* out = (float*)d_out;
    unsigned char* wsb = (unsigned char*)d_ws;

    hipMemsetAsync(d_ws, 0, ZERO_BYTES, stream);
    prep_kernel<<<1, 512, 0, stream>>>(condraw, input, wsb);
    repack_kernel<<<2048, 256, 0, stream>>>(W0, W1, W2, wsb);
    lstm_persistent<<<NBLK, NTH, 0, stream>>>(input, b0, b1, b2, Wd, bd,
                                              gamma, beta, out, wsb);
}